// Round 5
// baseline (465.071 us; speedup 1.0000x reference)
//
#include <hip/hip_runtime.h>

// TV Chambolle, image (8, 2048, 128) f32: 29 p-updates + final out = x + div(p) + bias.
// v = b*SB + t*ST + f.
//
// R5: temporal blocking (HH=4 iters/launch, cone EE=12 rows, RR=4 owned) with the
// column work SPLIT over 2 row-groups (512-thread blocks) to double occupancy
// (8 -> 16 waves/CU) and halve each thread's serial row chain.
// Group rg owns extended rows e in [6rg, 6rg+6). Interfaces per column:
//   P1[5]  (group0 -> group1, pre-out publish)
//   O[6]   (group1 -> group0, post-out publish)
// folded into the existing 2 barriers/iteration. Lane map unchanged from R4:
// lane = b + 8*fg (b fastest), b+-1 and f+-4 via shuffles, wave-crossing f via LDS.

#define BB 8
#define TT 2048
#define FF 128
#define NV (BB*TT*FF)        // 2,097,152
#define SB (TT*FF)           // 262144
#define ST FF                // 128
#define RR 4                 // owned t-rows per block
#define NBLK (TT/RR)         // 512
#define HH 4                 // fused iterations per launch
#define EE (RR + 2*HH)       // 12 extended rows
#define GR (EE/2)            // 6 rows per row-group

constexpr float TAU = 1.0f / 6.0f;

__device__ __forceinline__ float4 ld4(const float* p) { return *reinterpret_cast<const float4*>(p); }
__device__ __forceinline__ void st4(float* p, const float4& v) { *reinterpret_cast<float4*>(p) = v; }
__device__ __forceinline__ float4 shfl_up4(float4 v, int d) {
    return make_float4(__shfl_up(v.x, d), __shfl_up(v.y, d), __shfl_up(v.z, d), __shfl_up(v.w, d));
}
__device__ __forceinline__ float4 shfl_dn4(float4 v, int d) {
    return make_float4(__shfl_down(v.x, d), __shfl_down(v.y, d), __shfl_down(v.z, d), __shfl_down(v.w, d));
}

__global__ __launch_bounds__(512, 4)
void k_tb(const float* __restrict__ x, const float* __restrict__ pin,
          float* __restrict__ pout, const float* __restrict__ lam) {
    __shared__ float p2b[EE][4][8];              // p2.w at fg==7 per [row][wave][b]
    __shared__ float outx[EE][4][8];             // out.x at fg==0 per [row][wave][b]
    __shared__ __align__(16) float4 p1if[256];   // group0's P1[row 5] per column
    __shared__ __align__(16) float4 oif[256];    // group1's O[row 6] per column

    const int tid = threadIdx.x;
    const int rg  = tid >> 8;          // row-group 0/1
    const int c   = tid & 255;         // column id (same (b,f0) in both groups)
    const int b   = tid & 7;
    const int fg  = (tid >> 3) & 7;
    const int w   = (tid >> 6) & 3;    // f-section
    const int f0  = w * 32 + fg * 4;
    const int tb  = blockIdx.x * RR - HH;
    const int e0  = rg * GR;
    const int base = b * SB + f0;
    const float s = TAU / lam[0];

    float4 P0[GR], P1[GR], P2[GR], O[GR];

    // ---- load own extended rows into registers (zero-fill out-of-range) ----
    #pragma unroll
    for (int le = 0; le < GR; ++le) {
        const int t = tb + e0 + le;
        if (t >= 0 && t < TT) {
            const int v = base + t * ST;
            P0[le] = ld4(pin + v);
            P1[le] = ld4(pin + NV + v);
            P2[le] = ld4(pin + 2 * NV + v);
        } else {
            P0[le] = make_float4(0.f, 0.f, 0.f, 0.f);
            P1[le] = make_float4(0.f, 0.f, 0.f, 0.f);
            P2[le] = make_float4(0.f, 0.f, 0.f, 0.f);
        }
        O[le] = make_float4(0.f, 0.f, 0.f, 0.f);
    }

    #pragma unroll
    for (int k = 0; k < HH; ++k) {
        // ---- pre-out publishes (current p state) ----
        if (fg == 7) {
            #pragma unroll
            for (int le = 0; le < GR; ++le) {
                const int e = e0 + le;
                if (e >= k && e < EE - k) p2b[e][w][b] = P2[le].w;
            }
        }
        if (rg == 0) p1if[c] = P1[GR - 1];
        __syncthreads();

        // ---- out phase: own rows in [k+1, EE-k) ----
        #pragma unroll
        for (int le = 0; le < GR; ++le) {
            const int e = e0 + le;
            const int t = tb + e;
            if (e >= k + 1 && e < EE - k && t >= 0 && t < TT) {
                const float4 X = ld4(x + base + t * ST);
                float4 o;
                o.x = X.x - P0[le].x - P1[le].x - P2[le].x;
                o.y = X.y - P0[le].y - P1[le].y - P2[le].y + P2[le].x;
                o.z = X.z - P0[le].z - P1[le].z - P2[le].z + P2[le].y;
                o.w = X.w - P0[le].w - P1[le].w - P2[le].w + P2[le].z;
                float4 h0 = shfl_up4(P0[le], 1);                 // p0 at b-1
                if (b > 0) { o.x += h0.x; o.y += h0.y; o.z += h0.z; o.w += h0.w; }
                float4 pm1 = (le > 0) ? P1[le - 1] : p1if[c];    // p1 at t-1
                if (t > 0) { o.x += pm1.x; o.y += pm1.y; o.z += pm1.z; o.w += pm1.w; }
                float pw = __shfl_up(P2[le].w, 8);               // p2.w at f0-4
                if (fg == 0) pw = (w > 0) ? p2b[e][w - 1][b] : 0.0f;
                if (f0 > 0) o.x += pw;
                O[le] = o;
                if (fg == 0) outx[e][w][b] = o.x;
            }
        }
        if (rg == 1) oif[c] = O[0];                              // O at row 6
        __syncthreads();

        // ---- update phase: own rows in [k+1, EE-2-k] ----
        #pragma unroll
        for (int le = 0; le < GR; ++le) {
            const int e = e0 + le;
            const int t = tb + e;
            if (e >= k + 1 && e <= EE - 2 - k && t >= 0 && t < TT) {
                const float4 cc = O[le];
                float4 gT = make_float4(0.f, 0.f, 0.f, 0.f);
                if (t < TT - 1) {
                    float4 on = (le < GR - 1) ? O[le + 1] : oif[c];
                    gT.x = on.x - cc.x; gT.y = on.y - cc.y;
                    gT.z = on.z - cc.z; gT.w = on.w - cc.w;
                }
                const float4 nB = shfl_dn4(cc, 1);               // out at b+1
                float4 gB = make_float4(0.f, 0.f, 0.f, 0.f);
                if (b < BB - 1) {
                    gB.x = nB.x - cc.x; gB.y = nB.y - cc.y;
                    gB.z = nB.z - cc.z; gB.w = nB.w - cc.w;
                }
                float nxx = __shfl_down(cc.x, 8);                // out.x at f0+4
                if (fg == 7) nxx = (w < 3) ? outx[e][w + 1][b] : 0.0f;
                float4 gF;
                gF.x = cc.y - cc.x;
                gF.y = cc.z - cc.y;
                gF.z = cc.w - cc.z;
                gF.w = (f0 < FF - 4) ? (nxx - cc.w) : 0.f;

                float4 nb;
                nb.x = 1.f / (sqrtf(gB.x * gB.x + gT.x * gT.x + gF.x * gF.x) * s + 1.f);
                nb.y = 1.f / (sqrtf(gB.y * gB.y + gT.y * gT.y + gF.y * gF.y) * s + 1.f);
                nb.z = 1.f / (sqrtf(gB.z * gB.z + gT.z * gT.z + gF.z * gF.z) * s + 1.f);
                nb.w = 1.f / (sqrtf(gB.w * gB.w + gT.w * gT.w + gF.w * gF.w) * s + 1.f);

                P0[le].x = (P0[le].x - TAU * gB.x) * nb.x;
                P0[le].y = (P0[le].y - TAU * gB.y) * nb.y;
                P0[le].z = (P0[le].z - TAU * gB.z) * nb.z;
                P0[le].w = (P0[le].w - TAU * gB.w) * nb.w;
                P1[le].x = (P1[le].x - TAU * gT.x) * nb.x;
                P1[le].y = (P1[le].y - TAU * gT.y) * nb.y;
                P1[le].z = (P1[le].z - TAU * gT.z) * nb.z;
                P1[le].w = (P1[le].w - TAU * gT.w) * nb.w;
                P2[le].x = (P2[le].x - TAU * gF.x) * nb.x;
                P2[le].y = (P2[le].y - TAU * gF.y) * nb.y;
                P2[le].z = (P2[le].z - TAU * gF.z) * nb.z;
                P2[le].w = (P2[le].w - TAU * gF.w) * nb.w;
            }
        }
    }

    // ---- store owned rows e in [HH, HH+RR) ----
    #pragma unroll
    for (int le = 0; le < GR; ++le) {
        const int e = e0 + le;
        if (e >= HH && e < HH + RR) {
            const int v = base + (tb + e) * ST;
            st4(pout + v, P0[le]);
            st4(pout + NV + v, P1[le]);
            st4(pout + 2 * NV + v, P2[le]);
        }
    }
}

// ---- first iteration (p=0 -> out = x), proven ----
__global__ __launch_bounds__(256)
void k_first(const float* __restrict__ x, float* __restrict__ pout,
             const float* __restrict__ lam) {
    const int tid = threadIdx.x;
    const int t0  = blockIdx.x * 4;
    const float s = TAU / lam[0];
    const int f0 = (tid & 31) * 4;
    const int r  = (tid >> 5) & 3;
    const int b0 = tid >> 7;
    const int t  = t0 + r;
    #pragma unroll
    for (int k = 0; k < 4; ++k) {
        const int b = b0 + 2 * k;
        const int v = b * SB + t * ST + f0;
        float4 X = ld4(x + v);
        float4 gB = make_float4(0.f, 0.f, 0.f, 0.f);
        if (b < BB - 1) {
            float4 n = ld4(x + v + SB);
            gB = make_float4(n.x - X.x, n.y - X.y, n.z - X.z, n.w - X.w);
        }
        float4 gT = make_float4(0.f, 0.f, 0.f, 0.f);
        if (t < TT - 1) {
            float4 n = ld4(x + v + ST);
            gT = make_float4(n.x - X.x, n.y - X.y, n.z - X.z, n.w - X.w);
        }
        float4 gF;
        gF.x = X.y - X.x; gF.y = X.z - X.y; gF.z = X.w - X.z;
        gF.w = (f0 < FF - 4) ? (x[v + 4] - X.w) : 0.f;
        float4 nb;
        nb.x = 1.f / (sqrtf(gB.x * gB.x + gT.x * gT.x + gF.x * gF.x) * s + 1.f);
        nb.y = 1.f / (sqrtf(gB.y * gB.y + gT.y * gT.y + gF.y * gF.y) * s + 1.f);
        nb.z = 1.f / (sqrtf(gB.z * gB.z + gT.z * gT.z + gF.z * gF.z) * s + 1.f);
        nb.w = 1.f / (sqrtf(gB.w * gB.w + gT.w * gT.w + gF.w * gF.w) * s + 1.f);
        float4 q0, q1, q2;
        q0.x = -TAU * gB.x * nb.x;  q0.y = -TAU * gB.y * nb.y;
        q0.z = -TAU * gB.z * nb.z;  q0.w = -TAU * gB.w * nb.w;
        q1.x = -TAU * gT.x * nb.x;  q1.y = -TAU * gT.y * nb.y;
        q1.z = -TAU * gT.z * nb.z;  q1.w = -TAU * gT.w * nb.w;
        q2.x = -TAU * gF.x * nb.x;  q2.y = -TAU * gF.y * nb.y;
        q2.z = -TAU * gF.z * nb.z;  q2.w = -TAU * gF.w * nb.w;
        st4(pout + v, q0);
        st4(pout + NV + v, q1);
        st4(pout + 2 * NV + v, q2);
    }
}

// ---- final: out = x + div(p) + bias, proven ----
__global__ __launch_bounds__(256)
void k_final(const float* __restrict__ x, const float* __restrict__ pin,
             const float* __restrict__ bias, float* __restrict__ out) {
    const int gid = blockIdx.x * 256 + threadIdx.x;
    const int v = gid * 4;
    const int f0 = v & (FF - 1);
    const int t = (v >> 7) & (TT - 1);
    const int b = v >> 18;
    const float* p0 = pin;
    const float* p1 = pin + NV;
    const float* p2 = pin + 2 * NV;
    float4 X = ld4(x + v);
    float4 a0 = ld4(p0 + v), a1 = ld4(p1 + v), a2 = ld4(p2 + v);
    float ox = X.x - a0.x - a1.x - a2.x;
    float oy = X.y - a0.y - a1.y - a2.y + a2.x;
    float oz = X.z - a0.z - a1.z - a2.z + a2.y;
    float ow = X.w - a0.w - a1.w - a2.w + a2.z;
    if (b > 0) { float4 h = ld4(p0 + v - SB); ox += h.x; oy += h.y; oz += h.z; ow += h.w; }
    if (t > 0) { float4 h = ld4(p1 + v - ST); ox += h.x; oy += h.y; oz += h.z; ow += h.w; }
    if (f0 > 0) ox += p2[v - 1];
    float4 bi = ld4(bias + f0);
    st4(out + v, make_float4(ox + bi.x, oy + bi.y, oz + bi.z, ow + bi.w));
}

extern "C" void kernel_launch(void* const* d_in, const int* in_sizes, int n_in,
                              void* d_out, int out_size, void* d_ws, size_t ws_size,
                              hipStream_t stream) {
    const float* x    = (const float*)d_in[0];
    const float* lam  = (const float*)d_in[1];
    const float* bias = (const float*)d_in[2];
    float* out = (float*)d_out;

    float* pA = (float*)d_ws;
    float* pB = pA + 3 * NV;

    k_first<<<NBLK, 256, 0, stream>>>(x, pA, lam);
    float* pin = pA;
    float* pout = pB;
    for (int i = 0; i < 7; ++i) {
        k_tb<<<NBLK, 512, 0, stream>>>(x, pin, pout, lam);
        float* tmp = pin; pin = pout; pout = tmp;
    }
    k_final<<<NV / 1024, 256, 0, stream>>>(x, pin, bias, out);
}

// Round 6
// 417.669 us; speedup vs baseline: 1.1135x; 1.1135x over previous
//
#include <hip/hip_runtime.h>

// TV Chambolle, image (8, 2048, 128) f32: 29 p-updates + final out = x + div(p) + bias.
// v = b*SB + t*ST + f.
//
// R6: temporal blocking (HH=4 iters/launch, cone EE=12 rows, RR=4 owned), column
// chain split over 4 row-groups (1024-thread blocks, 16 waves/CU, 1 block/CU,
// VGPR hard cap 128). Group rg owns extended rows e in [3rg, 3rg+3): state =
// 9 float4 P + 3 float4 O + 3 float4 X ~= 100 VGPR -> fits the cap (R5's 2-way
// split at 512thr/4w spilled: VGPR=64, WRITE_SIZE doubled). Interfaces per
// column: P1[3rg+2] (pre-out publish) and O[3rg] (post-out publish), folded
// into the existing 2 barriers/iteration. Lane map: lane = b + 8*fg, b+-1 and
// f+-4 via shuffles, wave-crossing f via LDS.

#define BB 8
#define TT 2048
#define FF 128
#define NV (BB*TT*FF)        // 2,097,152
#define SB (TT*FF)           // 262144
#define ST FF                // 128
#define RR 4                 // owned t-rows per block
#define NBLK (TT/RR)         // 512
#define HH 4                 // fused iterations per launch
#define EE (RR + 2*HH)       // 12 extended rows
#define GR 3                 // rows per row-group (4 groups)

constexpr float TAU = 1.0f / 6.0f;

__device__ __forceinline__ float4 ld4(const float* p) { return *reinterpret_cast<const float4*>(p); }
__device__ __forceinline__ void st4(float* p, const float4& v) { *reinterpret_cast<float4*>(p) = v; }
__device__ __forceinline__ float4 shfl_up4(float4 v, int d) {
    return make_float4(__shfl_up(v.x, d), __shfl_up(v.y, d), __shfl_up(v.z, d), __shfl_up(v.w, d));
}
__device__ __forceinline__ float4 shfl_dn4(float4 v, int d) {
    return make_float4(__shfl_down(v.x, d), __shfl_down(v.y, d), __shfl_down(v.z, d), __shfl_down(v.w, d));
}

__global__ __launch_bounds__(1024, 4)
void k_tb(const float* __restrict__ x, const float* __restrict__ pin,
          float* __restrict__ pout, const float* __restrict__ lam) {
    __shared__ float p2b[EE][4][8];              // p2.w at fg==7 per [row][wavef][b]
    __shared__ float outx[EE][4][8];             // out.x at fg==0 per [row][wavef][b]
    __shared__ __align__(16) float4 p1if[4][256];// group rg's P1[row 3rg+2] per column
    __shared__ __align__(16) float4 oif[4][256]; // group rg's O[row 3rg] per column

    const int tid = threadIdx.x;
    const int rg  = tid >> 8;          // row-group 0..3
    const int c   = tid & 255;         // column id (same (b,f0) in all groups)
    const int b   = tid & 7;
    const int fg  = (tid >> 3) & 7;
    const int w   = (tid >> 6) & 3;    // f-section (wave id within group)
    const int f0  = w * 32 + fg * 4;
    const int tb  = blockIdx.x * RR - HH;
    const int e0  = rg * GR;
    const int base = b * SB + f0;
    const float s = TAU / lam[0];

    float4 P0[GR], P1[GR], P2[GR], O[GR], X[GR];

    // ---- load own extended rows + x into registers (zero-fill out-of-range) ----
    #pragma unroll
    for (int le = 0; le < GR; ++le) {
        const int t = tb + e0 + le;
        if (t >= 0 && t < TT) {
            const int v = base + t * ST;
            P0[le] = ld4(pin + v);
            P1[le] = ld4(pin + NV + v);
            P2[le] = ld4(pin + 2 * NV + v);
            X[le]  = ld4(x + v);
        } else {
            P0[le] = make_float4(0.f, 0.f, 0.f, 0.f);
            P1[le] = make_float4(0.f, 0.f, 0.f, 0.f);
            P2[le] = make_float4(0.f, 0.f, 0.f, 0.f);
            X[le]  = make_float4(0.f, 0.f, 0.f, 0.f);
        }
        O[le] = make_float4(0.f, 0.f, 0.f, 0.f);
    }

    #pragma unroll
    for (int k = 0; k < HH; ++k) {
        // ---- pre-out publishes (current p state) ----
        if (fg == 7) {
            #pragma unroll
            for (int le = 0; le < GR; ++le) {
                const int e = e0 + le;
                if (e >= k && e < EE - k) p2b[e][w][b] = P2[le].w;
            }
        }
        p1if[rg][c] = P1[GR - 1];
        __syncthreads();

        // ---- out phase: own rows with e in [k+1, EE-k) ----
        #pragma unroll
        for (int le = 0; le < GR; ++le) {
            const int e = e0 + le;
            const int t = tb + e;
            if (e >= k + 1 && e < EE - k && t >= 0 && t < TT) {
                float4 o;
                o.x = X[le].x - P0[le].x - P1[le].x - P2[le].x;
                o.y = X[le].y - P0[le].y - P1[le].y - P2[le].y + P2[le].x;
                o.z = X[le].z - P0[le].z - P1[le].z - P2[le].z + P2[le].y;
                o.w = X[le].w - P0[le].w - P1[le].w - P2[le].w + P2[le].z;
                float4 h0 = shfl_up4(P0[le], 1);                      // p0 at b-1
                if (b > 0) { o.x += h0.x; o.y += h0.y; o.z += h0.z; o.w += h0.w; }
                // p1 at t-1: in-group register or group interface (rg>=1 when le==0 here)
                float4 pm1 = (le > 0) ? P1[le - 1] : p1if[rg - 1][c];
                if (t > 0) { o.x += pm1.x; o.y += pm1.y; o.z += pm1.z; o.w += pm1.w; }
                float pw = __shfl_up(P2[le].w, 8);                    // p2.w at f0-4
                if (fg == 0) pw = (w > 0) ? p2b[e][w - 1][b] : 0.0f;
                if (f0 > 0) o.x += pw;
                O[le] = o;
                if (fg == 0) outx[e][w][b] = o.x;
            }
        }
        oif[rg][c] = O[0];
        __syncthreads();

        // ---- update phase: own rows with e in [k+1, EE-2-k] ----
        #pragma unroll
        for (int le = 0; le < GR; ++le) {
            const int e = e0 + le;
            const int t = tb + e;
            if (e >= k + 1 && e <= EE - 2 - k && t >= 0 && t < TT) {
                const float4 cc = O[le];
                float4 gT = make_float4(0.f, 0.f, 0.f, 0.f);
                if (t < TT - 1) {
                    // O at e+1: in-group register or group interface (rg<=2 when le==GR-1 here)
                    float4 on = (le < GR - 1) ? O[le + 1] : oif[rg + 1][c];
                    gT.x = on.x - cc.x; gT.y = on.y - cc.y;
                    gT.z = on.z - cc.z; gT.w = on.w - cc.w;
                }
                const float4 nB = shfl_dn4(cc, 1);                    // out at b+1
                float4 gB = make_float4(0.f, 0.f, 0.f, 0.f);
                if (b < BB - 1) {
                    gB.x = nB.x - cc.x; gB.y = nB.y - cc.y;
                    gB.z = nB.z - cc.z; gB.w = nB.w - cc.w;
                }
                float nxx = __shfl_down(cc.x, 8);                     // out.x at f0+4
                if (fg == 7) nxx = (w < 3) ? outx[e][w + 1][b] : 0.0f;
                float4 gF;
                gF.x = cc.y - cc.x;
                gF.y = cc.z - cc.y;
                gF.z = cc.w - cc.z;
                gF.w = (f0 < FF - 4) ? (nxx - cc.w) : 0.f;

                float4 nb;
                nb.x = 1.f / (sqrtf(gB.x * gB.x + gT.x * gT.x + gF.x * gF.x) * s + 1.f);
                nb.y = 1.f / (sqrtf(gB.y * gB.y + gT.y * gT.y + gF.y * gF.y) * s + 1.f);
                nb.z = 1.f / (sqrtf(gB.z * gB.z + gT.z * gT.z + gF.z * gF.z) * s + 1.f);
                nb.w = 1.f / (sqrtf(gB.w * gB.w + gT.w * gT.w + gF.w * gF.w) * s + 1.f);

                P0[le].x = (P0[le].x - TAU * gB.x) * nb.x;
                P0[le].y = (P0[le].y - TAU * gB.y) * nb.y;
                P0[le].z = (P0[le].z - TAU * gB.z) * nb.z;
                P0[le].w = (P0[le].w - TAU * gB.w) * nb.w;
                P1[le].x = (P1[le].x - TAU * gT.x) * nb.x;
                P1[le].y = (P1[le].y - TAU * gT.y) * nb.y;
                P1[le].z = (P1[le].z - TAU * gT.z) * nb.z;
                P1[le].w = (P1[le].w - TAU * gT.w) * nb.w;
                P2[le].x = (P2[le].x - TAU * gF.x) * nb.x;
                P2[le].y = (P2[le].y - TAU * gF.y) * nb.y;
                P2[le].z = (P2[le].z - TAU * gF.z) * nb.z;
                P2[le].w = (P2[le].w - TAU * gF.w) * nb.w;
            }
        }
    }

    // ---- store owned rows e in [HH, HH+RR) (always t-valid) ----
    #pragma unroll
    for (int le = 0; le < GR; ++le) {
        const int e = e0 + le;
        if (e >= HH && e < HH + RR) {
            const int v = base + (tb + e) * ST;
            st4(pout + v, P0[le]);
            st4(pout + NV + v, P1[le]);
            st4(pout + 2 * NV + v, P2[le]);
        }
    }
}

// ---- first iteration (p=0 -> out = x), proven ----
__global__ __launch_bounds__(256)
void k_first(const float* __restrict__ x, float* __restrict__ pout,
             const float* __restrict__ lam) {
    const int tid = threadIdx.x;
    const int t0  = blockIdx.x * 4;
    const float s = TAU / lam[0];
    const int f0 = (tid & 31) * 4;
    const int r  = (tid >> 5) & 3;
    const int b0 = tid >> 7;
    const int t  = t0 + r;
    #pragma unroll
    for (int k = 0; k < 4; ++k) {
        const int b = b0 + 2 * k;
        const int v = b * SB + t * ST + f0;
        float4 X = ld4(x + v);
        float4 gB = make_float4(0.f, 0.f, 0.f, 0.f);
        if (b < BB - 1) {
            float4 n = ld4(x + v + SB);
            gB = make_float4(n.x - X.x, n.y - X.y, n.z - X.z, n.w - X.w);
        }
        float4 gT = make_float4(0.f, 0.f, 0.f, 0.f);
        if (t < TT - 1) {
            float4 n = ld4(x + v + ST);
            gT = make_float4(n.x - X.x, n.y - X.y, n.z - X.z, n.w - X.w);
        }
        float4 gF;
        gF.x = X.y - X.x; gF.y = X.z - X.y; gF.z = X.w - X.z;
        gF.w = (f0 < FF - 4) ? (x[v + 4] - X.w) : 0.f;
        float4 nb;
        nb.x = 1.f / (sqrtf(gB.x * gB.x + gT.x * gT.x + gF.x * gF.x) * s + 1.f);
        nb.y = 1.f / (sqrtf(gB.y * gB.y + gT.y * gT.y + gF.y * gF.y) * s + 1.f);
        nb.z = 1.f / (sqrtf(gB.z * gB.z + gT.z * gT.z + gF.z * gF.z) * s + 1.f);
        nb.w = 1.f / (sqrtf(gB.w * gB.w + gT.w * gT.w + gF.w * gF.w) * s + 1.f);
        float4 q0, q1, q2;
        q0.x = -TAU * gB.x * nb.x;  q0.y = -TAU * gB.y * nb.y;
        q0.z = -TAU * gB.z * nb.z;  q0.w = -TAU * gB.w * nb.w;
        q1.x = -TAU * gT.x * nb.x;  q1.y = -TAU * gT.y * nb.y;
        q1.z = -TAU * gT.z * nb.z;  q1.w = -TAU * gT.w * nb.w;
        q2.x = -TAU * gF.x * nb.x;  q2.y = -TAU * gF.y * nb.y;
        q2.z = -TAU * gF.z * nb.z;  q2.w = -TAU * gF.w * nb.w;
        st4(pout + v, q0);
        st4(pout + NV + v, q1);
        st4(pout + 2 * NV + v, q2);
    }
}

// ---- final: out = x + div(p) + bias, proven ----
__global__ __launch_bounds__(256)
void k_final(const float* __restrict__ x, const float* __restrict__ pin,
             const float* __restrict__ bias, float* __restrict__ out) {
    const int gid = blockIdx.x * 256 + threadIdx.x;
    const int v = gid * 4;
    const int f0 = v & (FF - 1);
    const int t = (v >> 7) & (TT - 1);
    const int b = v >> 18;
    const float* p0 = pin;
    const float* p1 = pin + NV;
    const float* p2 = pin + 2 * NV;
    float4 X = ld4(x + v);
    float4 a0 = ld4(p0 + v), a1 = ld4(p1 + v), a2 = ld4(p2 + v);
    float ox = X.x - a0.x - a1.x - a2.x;
    float oy = X.y - a0.y - a1.y - a2.y + a2.x;
    float oz = X.z - a0.z - a1.z - a2.z + a2.y;
    float ow = X.w - a0.w - a1.w - a2.w + a2.z;
    if (b > 0) { float4 h = ld4(p0 + v - SB); ox += h.x; oy += h.y; oz += h.z; ow += h.w; }
    if (t > 0) { float4 h = ld4(p1 + v - ST); ox += h.x; oy += h.y; oz += h.z; ow += h.w; }
    if (f0 > 0) ox += p2[v - 1];
    float4 bi = ld4(bias + f0);
    st4(out + v, make_float4(ox + bi.x, oy + bi.y, oz + bi.z, ow + bi.w));
}

extern "C" void kernel_launch(void* const* d_in, const int* in_sizes, int n_in,
                              void* d_out, int out_size, void* d_ws, size_t ws_size,
                              hipStream_t stream) {
    const float* x    = (const float*)d_in[0];
    const float* lam  = (const float*)d_in[1];
    const float* bias = (const float*)d_in[2];
    float* out = (float*)d_out;

    float* pA = (float*)d_ws;
    float* pB = pA + 3 * NV;

    k_first<<<NBLK, 256, 0, stream>>>(x, pA, lam);
    float* pin = pA;
    float* pout = pB;
    for (int i = 0; i < 7; ++i) {
        k_tb<<<NBLK, 1024, 0, stream>>>(x, pin, pout, lam);
        float* tmp = pin; pin = pout; pout = tmp;
    }
    k_final<<<NV / 1024, 256, 0, stream>>>(x, pin, bias, out);
}

// Round 7
// 317.857 us; speedup vs baseline: 1.4631x; 1.3140x over previous
//
#include <hip/hip_runtime.h>

// TV Chambolle, image (8, 2048, 128) f32: 29 p-updates + final out = x + div(p) + bias.
// v = b*SB + t*ST + f.
//
// R7: temporal blocking, RR=8 owned t-rows, HH=4 fused iters, cone EE=16 rows,
// split over 2 row-groups (512-thr blocks, __launch_bounds__(512,2): reg cap 256
// so the 128-float row state stays in arch VGPRs -- R5's cap-128 memory-spilled,
// R6's 4-group AGPR-spilled). 23% fewer redundant cone rows than RR=4.
// k_tb_first folds iteration 1 (p==0 => out==x, no halo, barrier-free) + 4 cone
// iters into one launch. Lane map: lane = b + 8*fg; b+-1 and f+-4 via shuffles;
// wave-crossing f and the group interface via LDS inside the 2 barriers/iter.

#define BB 8
#define TT 2048
#define FF 128
#define NV (BB*TT*FF)        // 2,097,152
#define SB (TT*FF)           // 262144
#define ST FF                // 128
#define RR 8                 // owned t-rows per block
#define NBLK (TT/RR)         // 256
#define HH 4                 // cone iterations per launch
#define EE (RR + 2*HH)       // 16 extended rows
#define GR (EE/2)            // 8 rows per row-group

constexpr float TAU = 1.0f / 6.0f;

__device__ __forceinline__ float4 ld4(const float* p) { return *reinterpret_cast<const float4*>(p); }
__device__ __forceinline__ void st4(float* p, const float4& v) { *reinterpret_cast<float4*>(p) = v; }
__device__ __forceinline__ float4 shfl_up4(float4 v, int d) {
    return make_float4(__shfl_up(v.x, d), __shfl_up(v.y, d), __shfl_up(v.z, d), __shfl_up(v.w, d));
}
__device__ __forceinline__ float4 shfl_dn4(float4 v, int d) {
    return make_float4(__shfl_down(v.x, d), __shfl_down(v.y, d), __shfl_down(v.z, d), __shfl_down(v.w, d));
}
__device__ __forceinline__ float4 sub4(const float4& a, const float4& b) {
    return make_float4(a.x - b.x, a.y - b.y, a.z - b.z, a.w - b.w);
}
// 1/(|g|*s + 1), elementwise. v_sqrt_f32 + v_rcp_f32 (approx; tolerance has 12x headroom;
// sqrt(0)=0 keeps the all-zero-gradient corner exact: nb=1).
__device__ __forceinline__ float4 nbvec(const float4& gB, const float4& gT, const float4& gF, float s) {
    float4 nb;
    float q;
    q = gB.x * gB.x + gT.x * gT.x + gF.x * gF.x;
    nb.x = __builtin_amdgcn_rcpf(fmaf(__builtin_amdgcn_sqrtf(q), s, 1.f));
    q = gB.y * gB.y + gT.y * gT.y + gF.y * gF.y;
    nb.y = __builtin_amdgcn_rcpf(fmaf(__builtin_amdgcn_sqrtf(q), s, 1.f));
    q = gB.z * gB.z + gT.z * gT.z + gF.z * gF.z;
    nb.z = __builtin_amdgcn_rcpf(fmaf(__builtin_amdgcn_sqrtf(q), s, 1.f));
    q = gB.w * gB.w + gT.w * gT.w + gF.w * gF.w;
    nb.w = __builtin_amdgcn_rcpf(fmaf(__builtin_amdgcn_sqrtf(q), s, 1.f));
    return nb;
}

struct ConeShared {
    float p2b[EE][4][8];                 // p2.w at fg==7 per [row][w][b]
    float outx[EE][4][8];                // out.x at fg==0 per [row][w][b]
    float4 p1if[256];                    // group0's P1[row GR-1] per column
    float4 oif[256];                     // group1's O[row GR]   per column
};

// HH cone iterations. Before iter k, p rows [k, EE-k) are valid; after the loop,
// rows [HH, HH+RR) hold p advanced HH iterations.
__device__ __forceinline__ void run_cone(
    const float* __restrict__ x,
    float4 (&P0)[GR], float4 (&P1)[GR], float4 (&P2)[GR], float4 (&O)[GR],
    ConeShared& sh, int rg, int c, int b, int fg, int w, int f0,
    int tb, int e0, int base, float s)
{
    #pragma unroll
    for (int k = 0; k < HH; ++k) {
        // ---- pre-out publishes (current p state) ----
        if (fg == 7) {
            #pragma unroll
            for (int le = 0; le < GR; ++le) {
                const int e = e0 + le;
                if (e >= k && e < EE - k) sh.p2b[e][w][b] = P2[le].w;
            }
        }
        if (rg == 0) sh.p1if[c] = P1[GR - 1];
        __syncthreads();

        // ---- out phase: own rows with e in [k+1, EE-k) ----
        #pragma unroll
        for (int le = 0; le < GR; ++le) {
            const int e = e0 + le;
            const int t = tb + e;
            if (e >= k + 1 && e < EE - k && t >= 0 && t < TT) {
                const float4 X = ld4(x + base + t * ST);
                float4 o;
                o.x = X.x - P0[le].x - P1[le].x - P2[le].x;
                o.y = X.y - P0[le].y - P1[le].y - P2[le].y + P2[le].x;
                o.z = X.z - P0[le].z - P1[le].z - P2[le].z + P2[le].y;
                o.w = X.w - P0[le].w - P1[le].w - P2[le].w + P2[le].z;
                float4 h0 = shfl_up4(P0[le], 1);                  // p0 at b-1
                if (b > 0) { o.x += h0.x; o.y += h0.y; o.z += h0.z; o.w += h0.w; }
                float4 pm1 = (le > 0) ? P1[le - 1] : sh.p1if[c];  // p1 at t-1 (le==0 only for rg==1 here)
                if (t > 0) { o.x += pm1.x; o.y += pm1.y; o.z += pm1.z; o.w += pm1.w; }
                float pw = __shfl_up(P2[le].w, 8);                // p2.w at f0-4
                if (fg == 0) pw = (w > 0) ? sh.p2b[e][w - 1][b] : 0.0f;
                if (f0 > 0) o.x += pw;
                O[le] = o;
                if (fg == 0) sh.outx[e][w][b] = o.x;
            }
        }
        if (rg == 1) sh.oif[c] = O[0];                            // out at row GR
        __syncthreads();

        // ---- update phase: own rows with e in [k+1, EE-2-k] ----
        #pragma unroll
        for (int le = 0; le < GR; ++le) {
            const int e = e0 + le;
            const int t = tb + e;
            if (e >= k + 1 && e <= EE - 2 - k && t >= 0 && t < TT) {
                const float4 cc = O[le];
                float4 gT = make_float4(0.f, 0.f, 0.f, 0.f);
                if (t < TT - 1) {
                    float4 on = (le < GR - 1) ? O[le + 1] : sh.oif[c];  // le==GR-1 only for rg==0 here
                    gT = sub4(on, cc);
                }
                const float4 nB = shfl_dn4(cc, 1);                // out at b+1
                float4 gB = make_float4(0.f, 0.f, 0.f, 0.f);
                if (b < BB - 1) gB = sub4(nB, cc);
                float nxx = __shfl_down(cc.x, 8);                 // out.x at f0+4
                if (fg == 7) nxx = (w < 3) ? sh.outx[e][w + 1][b] : 0.0f;
                float4 gF;
                gF.x = cc.y - cc.x;
                gF.y = cc.z - cc.y;
                gF.z = cc.w - cc.z;
                gF.w = (f0 < FF - 4) ? (nxx - cc.w) : 0.f;

                const float4 nb = nbvec(gB, gT, gF, s);
                P0[le].x = fmaf(-TAU, gB.x, P0[le].x) * nb.x;
                P0[le].y = fmaf(-TAU, gB.y, P0[le].y) * nb.y;
                P0[le].z = fmaf(-TAU, gB.z, P0[le].z) * nb.z;
                P0[le].w = fmaf(-TAU, gB.w, P0[le].w) * nb.w;
                P1[le].x = fmaf(-TAU, gT.x, P1[le].x) * nb.x;
                P1[le].y = fmaf(-TAU, gT.y, P1[le].y) * nb.y;
                P1[le].z = fmaf(-TAU, gT.z, P1[le].z) * nb.z;
                P1[le].w = fmaf(-TAU, gT.w, P1[le].w) * nb.w;
                P2[le].x = fmaf(-TAU, gF.x, P2[le].x) * nb.x;
                P2[le].y = fmaf(-TAU, gF.y, P2[le].y) * nb.y;
                P2[le].z = fmaf(-TAU, gF.z, P2[le].z) * nb.z;
                P2[le].w = fmaf(-TAU, gF.w, P2[le].w) * nb.w;
            }
        }
    }
}

// Generic launch: 4 cone iterations on existing p.
__global__ __launch_bounds__(512, 2)
void k_tb(const float* __restrict__ x, const float* __restrict__ pin,
          float* __restrict__ pout, const float* __restrict__ lam) {
    __shared__ ConeShared sh;
    const int tid = threadIdx.x;
    const int rg  = tid >> 8;
    const int c   = tid & 255;
    const int b   = tid & 7;
    const int fg  = (tid >> 3) & 7;
    const int w   = (tid >> 6) & 3;
    const int f0  = w * 32 + fg * 4;
    const int tb  = blockIdx.x * RR - HH;
    const int e0  = rg * GR;
    const int base = b * SB + f0;
    const float s = TAU / lam[0];

    float4 P0[GR], P1[GR], P2[GR], O[GR];
    #pragma unroll
    for (int le = 0; le < GR; ++le) {
        const int t = tb + e0 + le;
        if (t >= 0 && t < TT) {
            const int v = base + t * ST;
            P0[le] = ld4(pin + v);
            P1[le] = ld4(pin + NV + v);
            P2[le] = ld4(pin + 2 * NV + v);
        } else {
            P0[le] = make_float4(0.f, 0.f, 0.f, 0.f);
            P1[le] = make_float4(0.f, 0.f, 0.f, 0.f);
            P2[le] = make_float4(0.f, 0.f, 0.f, 0.f);
        }
        O[le] = make_float4(0.f, 0.f, 0.f, 0.f);
    }

    run_cone(x, P0, P1, P2, O, sh, rg, c, b, fg, w, f0, tb, e0, base, s);

    #pragma unroll
    for (int le = 0; le < GR; ++le) {
        const int e = e0 + le;
        if (e >= HH && e < HH + RR) {
            const int v = base + (tb + e) * ST;
            st4(pout + v, P0[le]);
            st4(pout + NV + v, P1[le]);
            st4(pout + 2 * NV + v, P2[le]);
        }
    }
}

// First launch: iteration 1 from p==0 (out==x: no halo, no barriers) + 4 cone iters.
__global__ __launch_bounds__(512, 2)
void k_tb_first(const float* __restrict__ x, float* __restrict__ pout,
                const float* __restrict__ lam) {
    __shared__ ConeShared sh;
    const int tid = threadIdx.x;
    const int rg  = tid >> 8;
    const int c   = tid & 255;
    const int b   = tid & 7;
    const int fg  = (tid >> 3) & 7;
    const int w   = (tid >> 6) & 3;
    const int f0  = w * 32 + fg * 4;
    const int tb  = blockIdx.x * RR - HH;
    const int e0  = rg * GR;
    const int base = b * SB + f0;
    const float s = TAU / lam[0];

    float4 P0[GR], P1[GR], P2[GR], O[GR];
    float4 Xr[GR], XH;
    #pragma unroll
    for (int le = 0; le < GR; ++le) {
        const int t = tb + e0 + le;
        Xr[le] = (t >= 0 && t < TT) ? ld4(x + base + t * ST) : make_float4(0.f, 0.f, 0.f, 0.f);
        O[le] = make_float4(0.f, 0.f, 0.f, 0.f);
    }
    {
        const int t = tb + e0 + GR;
        XH = (t >= 0 && t < TT) ? ld4(x + base + t * ST) : make_float4(0.f, 0.f, 0.f, 0.f);
    }

    // ---- iteration 1: p = -TAU*grad(x) / (|grad(x)|*s + 1), all t-valid rows ----
    #pragma unroll
    for (int le = 0; le < GR; ++le) {
        const int t = tb + e0 + le;
        if (t >= 0 && t < TT) {
            const float4 cc = Xr[le];
            float4 gT = make_float4(0.f, 0.f, 0.f, 0.f);
            if (t < TT - 1) {
                float4 nxt = (le < GR - 1) ? Xr[le + 1] : XH;
                gT = sub4(nxt, cc);
            }
            const float4 nB = shfl_dn4(cc, 1);
            float4 gB = make_float4(0.f, 0.f, 0.f, 0.f);
            if (b < BB - 1) gB = sub4(nB, cc);
            float4 gF;
            gF.x = cc.y - cc.x;
            gF.y = cc.z - cc.y;
            gF.z = cc.w - cc.z;
            gF.w = (f0 < FF - 4) ? (x[base + t * ST + 4] - cc.w) : 0.f;  // any f crossing via direct load
            const float4 nb = nbvec(gB, gT, gF, s);
            P0[le] = make_float4(-TAU * gB.x * nb.x, -TAU * gB.y * nb.y,
                                 -TAU * gB.z * nb.z, -TAU * gB.w * nb.w);
            P1[le] = make_float4(-TAU * gT.x * nb.x, -TAU * gT.y * nb.y,
                                 -TAU * gT.z * nb.z, -TAU * gT.w * nb.w);
            P2[le] = make_float4(-TAU * gF.x * nb.x, -TAU * gF.y * nb.y,
                                 -TAU * gF.z * nb.z, -TAU * gF.w * nb.w);
        } else {
            P0[le] = make_float4(0.f, 0.f, 0.f, 0.f);
            P1[le] = make_float4(0.f, 0.f, 0.f, 0.f);
            P2[le] = make_float4(0.f, 0.f, 0.f, 0.f);
        }
    }

    run_cone(x, P0, P1, P2, O, sh, rg, c, b, fg, w, f0, tb, e0, base, s);

    #pragma unroll
    for (int le = 0; le < GR; ++le) {
        const int e = e0 + le;
        if (e >= HH && e < HH + RR) {
            const int v = base + (tb + e) * ST;
            st4(pout + v, P0[le]);
            st4(pout + NV + v, P1[le]);
            st4(pout + 2 * NV + v, P2[le]);
        }
    }
}

// ---- final: out = x + div(p) + bias, proven ----
__global__ __launch_bounds__(256)
void k_final(const float* __restrict__ x, const float* __restrict__ pin,
             const float* __restrict__ bias, float* __restrict__ out) {
    const int gid = blockIdx.x * 256 + threadIdx.x;
    const int v = gid * 4;
    const int f0 = v & (FF - 1);
    const int t = (v >> 7) & (TT - 1);
    const int b = v >> 18;
    const float* p0 = pin;
    const float* p1 = pin + NV;
    const float* p2 = pin + 2 * NV;
    float4 X = ld4(x + v);
    float4 a0 = ld4(p0 + v), a1 = ld4(p1 + v), a2 = ld4(p2 + v);
    float ox = X.x - a0.x - a1.x - a2.x;
    float oy = X.y - a0.y - a1.y - a2.y + a2.x;
    float oz = X.z - a0.z - a1.z - a2.z + a2.y;
    float ow = X.w - a0.w - a1.w - a2.w + a2.z;
    if (b > 0) { float4 h = ld4(p0 + v - SB); ox += h.x; oy += h.y; oz += h.z; ow += h.w; }
    if (t > 0) { float4 h = ld4(p1 + v - ST); ox += h.x; oy += h.y; oz += h.z; ow += h.w; }
    if (f0 > 0) ox += p2[v - 1];
    float4 bi = ld4(bias + f0);
    st4(out + v, make_float4(ox + bi.x, oy + bi.y, oz + bi.z, ow + bi.w));
}

extern "C" void kernel_launch(void* const* d_in, const int* in_sizes, int n_in,
                              void* d_out, int out_size, void* d_ws, size_t ws_size,
                              hipStream_t stream) {
    const float* x    = (const float*)d_in[0];
    const float* lam  = (const float*)d_in[1];
    const float* bias = (const float*)d_in[2];
    float* out = (float*)d_out;

    float* pA = (float*)d_ws;
    float* pB = pA + 3 * NV;

    // iterations 1..5 in one launch (iter0 specialization + 4 cone iters)
    k_tb_first<<<NBLK, 512, 0, stream>>>(x, pA, lam);
    // 6 more launches x 4 iterations = 24 -> 29 total
    float* pin = pA;
    float* pout = pB;
    for (int i = 0; i < 6; ++i) {
        k_tb<<<NBLK, 512, 0, stream>>>(x, pin, pout, lam);
        float* tmp = pin; pin = pout; pout = tmp;
    }
    k_final<<<NV / 1024, 256, 0, stream>>>(x, pin, bias, out);
}

// Round 8
// 270.451 us; speedup vs baseline: 1.7196x; 1.1753x over previous
//
#include <hip/hip_runtime.h>

// TV Chambolle, image (8, 2048, 128) f32: 29 p-updates + final out = x + div(p) + bias.
// v = b*SB + t*ST + f.
//
// R8 = R7 (RR=8, HH=4, EE=16, 2 row-groups, 512-thr blocks, (512,2)) with
// control flow constant-folded:
//  - cone phases templated on RG: e = RG*GR+le and all e-vs-k guards compile-time.
//    Barriers remain at TOP level (block-uniform); the rg branch wraps only
//    barrier-free compute, so no divergent-barrier hazard.
//  - interior/edge block specialization: blocks 1..254 run with zero t-guards
//    (t in [4,2043], provably valid); blocks 0 and 255 run the guarded variant.
//  - Xr[GR] preloaded once per dispatch (R7 reloaded x every iteration).
// Lane map: lane = b + 8*fg; b+-1 and f+-4 via shuffles; wave-crossing f and the
// group interface via LDS inside the 2 barriers/iter.

#define BB 8
#define TT 2048
#define FF 128
#define NV (BB*TT*FF)        // 2,097,152
#define SB (TT*FF)           // 262144
#define ST FF                // 128
#define RR 8                 // owned t-rows per block
#define NBLK (TT/RR)         // 256
#define HH 4                 // cone iterations per launch
#define EE (RR + 2*HH)       // 16 extended rows
#define GR (EE/2)            // 8 rows per row-group

constexpr float TAU = 1.0f / 6.0f;

__device__ __forceinline__ float4 ld4(const float* p) { return *reinterpret_cast<const float4*>(p); }
__device__ __forceinline__ void st4(float* p, const float4& v) { *reinterpret_cast<float4*>(p) = v; }
__device__ __forceinline__ float4 shfl_up4(float4 v, int d) {
    return make_float4(__shfl_up(v.x, d), __shfl_up(v.y, d), __shfl_up(v.z, d), __shfl_up(v.w, d));
}
__device__ __forceinline__ float4 shfl_dn4(float4 v, int d) {
    return make_float4(__shfl_down(v.x, d), __shfl_down(v.y, d), __shfl_down(v.z, d), __shfl_down(v.w, d));
}
__device__ __forceinline__ float4 sub4(const float4& a, const float4& b) {
    return make_float4(a.x - b.x, a.y - b.y, a.z - b.z, a.w - b.w);
}
__device__ __forceinline__ float4 f4z() { return make_float4(0.f, 0.f, 0.f, 0.f); }
// 1/(|g|*s + 1) elementwise; v_sqrt_f32 + v_rcp_f32 approx (12x tolerance headroom,
// sqrt(0)=0 keeps the zero-gradient corner exact).
__device__ __forceinline__ float4 nbvec(const float4& gB, const float4& gT, const float4& gF, float s) {
    float4 nb; float q;
    q = gB.x * gB.x + gT.x * gT.x + gF.x * gF.x;
    nb.x = __builtin_amdgcn_rcpf(fmaf(__builtin_amdgcn_sqrtf(q), s, 1.f));
    q = gB.y * gB.y + gT.y * gT.y + gF.y * gF.y;
    nb.y = __builtin_amdgcn_rcpf(fmaf(__builtin_amdgcn_sqrtf(q), s, 1.f));
    q = gB.z * gB.z + gT.z * gT.z + gF.z * gF.z;
    nb.z = __builtin_amdgcn_rcpf(fmaf(__builtin_amdgcn_sqrtf(q), s, 1.f));
    q = gB.w * gB.w + gT.w * gT.w + gF.w * gF.w;
    nb.w = __builtin_amdgcn_rcpf(fmaf(__builtin_amdgcn_sqrtf(q), s, 1.f));
    return nb;
}

struct ConeShared {
    float p2b[EE][4][8];                 // p2.w at fg==7 per [row][w][b]
    float outx[EE][4][8];                // out.x at fg==0 per [row][w][b]
    float4 p1if[256];                    // group0's P1[row GR-1] per column
    float4 oif[256];                     // group1's O[row GR]   per column
};

// ---- cone phases, RG/edge compile-time (no barriers inside) ----
template<int RG>
__device__ __forceinline__ void publish_p(int k, float4 (&P1)[GR], float4 (&P2)[GR],
                                          ConeShared& sh, int c, int b, int fg, int w) {
    if (fg == 7) {
        #pragma unroll
        for (int le = 0; le < GR; ++le) {
            const int e = RG * GR + le;
            if (e >= k && e < EE - k) sh.p2b[e][w][b] = P2[le].w;
        }
    }
    if (RG == 0) sh.p1if[c] = P1[GR - 1];
}

template<int RG, bool ELO, bool EHI>
__device__ __forceinline__ void phase_out(
    int k, const float4 (&Xr)[GR],
    float4 (&P0)[GR], float4 (&P1)[GR], float4 (&P2)[GR], float4 (&O)[GR],
    ConeShared& sh, int c, int b, int fg, int w, int f0, int tb) {
    #pragma unroll
    for (int le = 0; le < GR; ++le) {
        const int e = RG * GR + le;
        if (e < k + 1 || e >= EE - k) continue;          // compile-time row kill
        const int t = tb + e;
        if ((ELO && t < 0) || (EHI && t >= TT)) continue;
        const float4 X = Xr[le];
        float4 o;
        o.x = X.x - P0[le].x - P1[le].x - P2[le].x;
        o.y = X.y - P0[le].y - P1[le].y - P2[le].y + P2[le].x;
        o.z = X.z - P0[le].z - P1[le].z - P2[le].z + P2[le].y;
        o.w = X.w - P0[le].w - P1[le].w - P2[le].w + P2[le].z;
        float4 h0 = shfl_up4(P0[le], 1);                 // p0 at b-1
        if (b > 0) { o.x += h0.x; o.y += h0.y; o.z += h0.z; o.w += h0.w; }
        float4 pm1 = (le > 0) ? P1[le - 1] : sh.p1if[c]; // p1 at t-1 (LDS only for RG=1,le=0)
        if (!ELO || t > 0) { o.x += pm1.x; o.y += pm1.y; o.z += pm1.z; o.w += pm1.w; }
        float pw = __shfl_up(P2[le].w, 8);               // p2.w at f0-4
        if (fg == 0) pw = (w > 0) ? sh.p2b[e][w - 1][b] : 0.0f;
        if (f0 > 0) o.x += pw;
        O[le] = o;
        if (fg == 0) sh.outx[e][w][b] = o.x;
    }
}

template<int RG, bool ELO, bool EHI>
__device__ __forceinline__ void phase_upd(
    int k, float4 (&P0)[GR], float4 (&P1)[GR], float4 (&P2)[GR], float4 (&O)[GR],
    ConeShared& sh, int c, int b, int fg, int w, int f0, int tb, float s) {
    #pragma unroll
    for (int le = 0; le < GR; ++le) {
        const int e = RG * GR + le;
        if (e < k + 1 || e > EE - 2 - k) continue;       // compile-time row kill
        const int t = tb + e;
        if ((ELO && t < 0) || (EHI && t >= TT)) continue;
        const float4 cc = O[le];
        float4 on = (le < GR - 1) ? O[le + 1] : sh.oif[c];  // oif only for RG=0,le=GR-1
        float4 gT = f4z();
        if (!EHI || t < TT - 1) gT = sub4(on, cc);
        const float4 nB = shfl_dn4(cc, 1);               // out at b+1
        float4 gB = f4z();
        if (b < BB - 1) gB = sub4(nB, cc);
        float nxx = __shfl_down(cc.x, 8);                // out.x at f0+4
        if (fg == 7) nxx = (w < 3) ? sh.outx[e][w + 1][b] : 0.0f;
        float4 gF;
        gF.x = cc.y - cc.x;
        gF.y = cc.z - cc.y;
        gF.z = cc.w - cc.z;
        gF.w = (f0 < FF - 4) ? (nxx - cc.w) : 0.f;
        const float4 nb = nbvec(gB, gT, gF, s);
        P0[le].x = fmaf(-TAU, gB.x, P0[le].x) * nb.x;
        P0[le].y = fmaf(-TAU, gB.y, P0[le].y) * nb.y;
        P0[le].z = fmaf(-TAU, gB.z, P0[le].z) * nb.z;
        P0[le].w = fmaf(-TAU, gB.w, P0[le].w) * nb.w;
        P1[le].x = fmaf(-TAU, gT.x, P1[le].x) * nb.x;
        P1[le].y = fmaf(-TAU, gT.y, P1[le].y) * nb.y;
        P1[le].z = fmaf(-TAU, gT.z, P1[le].z) * nb.z;
        P1[le].w = fmaf(-TAU, gT.w, P1[le].w) * nb.w;
        P2[le].x = fmaf(-TAU, gF.x, P2[le].x) * nb.x;
        P2[le].y = fmaf(-TAU, gF.y, P2[le].y) * nb.y;
        P2[le].z = fmaf(-TAU, gF.z, P2[le].z) * nb.z;
        P2[le].w = fmaf(-TAU, gF.w, P2[le].w) * nb.w;
    }
}

// barriers live here, block-uniform; rg branches wrap only barrier-free compute
template<bool ELO, bool EHI>
__device__ __forceinline__ void cone_run(
    const float4 (&Xr)[GR],
    float4 (&P0)[GR], float4 (&P1)[GR], float4 (&P2)[GR], float4 (&O)[GR],
    ConeShared& sh, int rg, int c, int b, int fg, int w, int f0, int tb, float s) {
    #pragma unroll
    for (int k = 0; k < HH; ++k) {
        if (rg == 0) publish_p<0>(k, P1, P2, sh, c, b, fg, w);
        else         publish_p<1>(k, P1, P2, sh, c, b, fg, w);
        __syncthreads();
        if (rg == 0) phase_out<0, ELO, EHI>(k, Xr, P0, P1, P2, O, sh, c, b, fg, w, f0, tb);
        else         phase_out<1, ELO, EHI>(k, Xr, P0, P1, P2, O, sh, c, b, fg, w, f0, tb);
        if (rg == 1) sh.oif[c] = O[0];                   // out at row GR
        __syncthreads();
        if (rg == 0) phase_upd<0, ELO, EHI>(k, P0, P1, P2, O, sh, c, b, fg, w, f0, tb, s);
        else         phase_upd<1, ELO, EHI>(k, P0, P1, P2, O, sh, c, b, fg, w, f0, tb, s);
    }
}

template<bool ELO, bool EHI>
__device__ __forceinline__ void tb_main(
    const float* __restrict__ x, const float* __restrict__ pin, float* __restrict__ pout,
    ConeShared& sh, int rg, int c, int b, int fg, int w, int f0, int tb, int e0,
    int base, float s) {
    float4 P0[GR], P1[GR], P2[GR], O[GR], Xr[GR];
    #pragma unroll
    for (int le = 0; le < GR; ++le) {
        const int t = tb + e0 + le;
        if ((!ELO || t >= 0) && (!EHI || t < TT)) {
            const int v = base + t * ST;
            P0[le] = ld4(pin + v);
            P1[le] = ld4(pin + NV + v);
            P2[le] = ld4(pin + 2 * NV + v);
            Xr[le] = ld4(x + v);
        } else {
            P0[le] = f4z(); P1[le] = f4z(); P2[le] = f4z(); Xr[le] = f4z();
        }
        O[le] = f4z();
    }
    cone_run<ELO, EHI>(Xr, P0, P1, P2, O, sh, rg, c, b, fg, w, f0, tb, s);
    #pragma unroll
    for (int le = 0; le < GR; ++le) {
        const int e = e0 + le;
        if (e >= HH && e < HH + RR) {                    // owned rows: t always valid
            const int v = base + (tb + e) * ST;
            st4(pout + v, P0[le]);
            st4(pout + NV + v, P1[le]);
            st4(pout + 2 * NV + v, P2[le]);
        }
    }
}

__global__ __launch_bounds__(512, 2)
void k_tb(const float* __restrict__ x, const float* __restrict__ pin,
          float* __restrict__ pout, const float* __restrict__ lam) {
    __shared__ ConeShared sh;
    const int tid = threadIdx.x;
    const int blk = blockIdx.x;
    const int rg  = tid >> 8;
    const int c   = tid & 255;
    const int b   = tid & 7;
    const int fg  = (tid >> 3) & 7;
    const int w   = (tid >> 6) & 3;
    const int f0  = w * 32 + fg * 4;
    const int tb  = blk * RR - HH;
    const int e0  = rg * GR;
    const int base = b * SB + f0;
    const float s = TAU / lam[0];
    if (blk == 0 || blk == NBLK - 1)
        tb_main<true, true>(x, pin, pout, sh, rg, c, b, fg, w, f0, tb, e0, base, s);
    else
        tb_main<false, false>(x, pin, pout, sh, rg, c, b, fg, w, f0, tb, e0, base, s);
}

// First launch: iteration 1 from p==0 (out==x, barrier-free) + 4 cone iters.
template<bool ELO, bool EHI>
__device__ __forceinline__ void tb_first_main(
    const float* __restrict__ x, float* __restrict__ pout,
    ConeShared& sh, int rg, int c, int b, int fg, int w, int f0, int tb, int e0,
    int base, float s) {
    float4 P0[GR], P1[GR], P2[GR], O[GR], Xr[GR], XH;
    #pragma unroll
    for (int le = 0; le < GR; ++le) {
        const int t = tb + e0 + le;
        Xr[le] = ((!ELO || t >= 0) && (!EHI || t < TT)) ? ld4(x + base + t * ST) : f4z();
        O[le] = f4z();
    }
    {
        const int t = tb + e0 + GR;
        XH = ((!ELO || t >= 0) && (!EHI || t < TT)) ? ld4(x + base + t * ST) : f4z();
    }
    // iteration 1: p = -TAU*grad(x) / (|grad(x)|*s + 1) on all valid rows
    #pragma unroll
    for (int le = 0; le < GR; ++le) {
        const int t = tb + e0 + le;
        if ((!ELO || t >= 0) && (!EHI || t < TT)) {
            const float4 cc = Xr[le];
            float4 nxt = (le < GR - 1) ? Xr[le + 1] : XH;
            float4 gT = f4z();
            if (!EHI || t < TT - 1) gT = sub4(nxt, cc);
            const float4 nB = shfl_dn4(cc, 1);
            float4 gB = f4z();
            if (b < BB - 1) gB = sub4(nB, cc);
            float4 gF;
            gF.x = cc.y - cc.x;
            gF.y = cc.z - cc.y;
            gF.z = cc.w - cc.z;
            gF.w = (f0 < FF - 4) ? (x[base + t * ST + 4] - cc.w) : 0.f;
            const float4 nb = nbvec(gB, gT, gF, s);
            P0[le] = make_float4(-TAU * gB.x * nb.x, -TAU * gB.y * nb.y,
                                 -TAU * gB.z * nb.z, -TAU * gB.w * nb.w);
            P1[le] = make_float4(-TAU * gT.x * nb.x, -TAU * gT.y * nb.y,
                                 -TAU * gT.z * nb.z, -TAU * gT.w * nb.w);
            P2[le] = make_float4(-TAU * gF.x * nb.x, -TAU * gF.y * nb.y,
                                 -TAU * gF.z * nb.z, -TAU * gF.w * nb.w);
        } else {
            P0[le] = f4z(); P1[le] = f4z(); P2[le] = f4z();
        }
    }
    cone_run<ELO, EHI>(Xr, P0, P1, P2, O, sh, rg, c, b, fg, w, f0, tb, s);
    #pragma unroll
    for (int le = 0; le < GR; ++le) {
        const int e = e0 + le;
        if (e >= HH && e < HH + RR) {
            const int v = base + (tb + e) * ST;
            st4(pout + v, P0[le]);
            st4(pout + NV + v, P1[le]);
            st4(pout + 2 * NV + v, P2[le]);
        }
    }
}

__global__ __launch_bounds__(512, 2)
void k_tb_first(const float* __restrict__ x, float* __restrict__ pout,
                const float* __restrict__ lam) {
    __shared__ ConeShared sh;
    const int tid = threadIdx.x;
    const int blk = blockIdx.x;
    const int rg  = tid >> 8;
    const int c   = tid & 255;
    const int b   = tid & 7;
    const int fg  = (tid >> 3) & 7;
    const int w   = (tid >> 6) & 3;
    const int f0  = w * 32 + fg * 4;
    const int tb  = blk * RR - HH;
    const int e0  = rg * GR;
    const int base = b * SB + f0;
    const float s = TAU / lam[0];
    if (blk == 0 || blk == NBLK - 1)
        tb_first_main<true, true>(x, pout, sh, rg, c, b, fg, w, f0, tb, e0, base, s);
    else
        tb_first_main<false, false>(x, pout, sh, rg, c, b, fg, w, f0, tb, e0, base, s);
}

// ---- final: out = x + div(p) + bias, proven ----
__global__ __launch_bounds__(256)
void k_final(const float* __restrict__ x, const float* __restrict__ pin,
             const float* __restrict__ bias, float* __restrict__ out) {
    const int gid = blockIdx.x * 256 + threadIdx.x;
    const int v = gid * 4;
    const int f0 = v & (FF - 1);
    const int t = (v >> 7) & (TT - 1);
    const int b = v >> 18;
    const float* p0 = pin;
    const float* p1 = pin + NV;
    const float* p2 = pin + 2 * NV;
    float4 X = ld4(x + v);
    float4 a0 = ld4(p0 + v), a1 = ld4(p1 + v), a2 = ld4(p2 + v);
    float ox = X.x - a0.x - a1.x - a2.x;
    float oy = X.y - a0.y - a1.y - a2.y + a2.x;
    float oz = X.z - a0.z - a1.z - a2.z + a2.y;
    float ow = X.w - a0.w - a1.w - a2.w + a2.z;
    if (b > 0) { float4 h = ld4(p0 + v - SB); ox += h.x; oy += h.y; oz += h.z; ow += h.w; }
    if (t > 0) { float4 h = ld4(p1 + v - ST); ox += h.x; oy += h.y; oz += h.z; ow += h.w; }
    if (f0 > 0) ox += p2[v - 1];
    float4 bi = ld4(bias + f0);
    st4(out + v, make_float4(ox + bi.x, oy + bi.y, oz + bi.z, ow + bi.w));
}

extern "C" void kernel_launch(void* const* d_in, const int* in_sizes, int n_in,
                              void* d_out, int out_size, void* d_ws, size_t ws_size,
                              hipStream_t stream) {
    const float* x    = (const float*)d_in[0];
    const float* lam  = (const float*)d_in[1];
    const float* bias = (const float*)d_in[2];
    float* out = (float*)d_out;

    float* pA = (float*)d_ws;
    float* pB = pA + 3 * NV;

    // iterations 1..5 in one launch (iter-1 specialization + 4 cone iters)
    k_tb_first<<<NBLK, 512, 0, stream>>>(x, pA, lam);
    // 6 more launches x 4 iterations = 24 -> 29 total
    float* pin = pA;
    float* pout = pB;
    for (int i = 0; i < 6; ++i) {
        k_tb<<<NBLK, 512, 0, stream>>>(x, pin, pout, lam);
        float* tmp = pin; pin = pout; pout = tmp;
    }
    k_final<<<NV / 1024, 256, 0, stream>>>(x, pin, bias, out);
}